// Round 8
// baseline (413.439 us; speedup 1.0000x reference)
//
#include <hip/hip_runtime.h>

#define VOCAB 50000
#define SEQ   200
#define NF4   (VOCAB / 4)      // 12500 float4 stores per row
#define H     4                // register count-slots per owner thread

// One block per batch row, ONE-PASS, REGISTER-SPARSE structure: the store
// stream is a pure register zero/insert stream -- no ds_read, no histogram,
// no atomics, nothing memory-dependent between global_store_dwordx4's.
//
// Ownership map: phase-C iteration i (= t + 256k) writes elements 4i..4i+3,
// so token idx belongs to owner thread (idx>>2)&255 at slot key
// ((idx>>10)<<2)|(idx&3). Expected distinct tokens per owner ~0.78
// (Poisson), so H=4 register slots cover ~all threads; overflow (~1e-3 per
// thread) goes to an exact LDS patch list applied after the stream drains.
// Counts are exact u8 (<=200), so no count-cap patch is needed at all.
__global__ __launch_bounds__(256) void MultihotEmbedding_16458314678493_kernel(
    const int* __restrict__ x, float* __restrict__ out) {
  __shared__ int lidx[SEQ];
  __shared__ unsigned slots[H * 256];   // [slot][owner] -> bank-stride 1
  __shared__ unsigned nslot[256];
  __shared__ unsigned ovflist[SEQ];
  __shared__ unsigned ovfn;

  const int row = blockIdx.x;
  const int t = threadIdx.x;
  float* __restrict__ orow = out + (size_t)row * VOCAB;

  // Phase A: stage indices (int4), init slot sentinels + counters.
  if (t < SEQ / 4) ((int4*)lidx)[t] = ((const int4*)(x + row * SEQ))[t];
#pragma unroll
  for (int s = 0; s < H; ++s) slots[s * 256 + t] = 0xFF00u;  // key=255: never matches (real keys <= 195)
  nslot[t] = 0u;
  if (t == 0) ovfn = 0u;
  __syncthreads();

  // Phase B: dedupe-count (R7's proven int4-broadcast loop), then route
  // each distinct token's (key,cnt) to its owner thread's slot cell.
  int myidx = -1, cnt = 0, first = 1;
  if (t < SEQ) myidx = lidx[t];
  for (int jj = 0; jj < SEQ / 4; ++jj) {
    const int4 q = ((const int4*)lidx)[jj];
    const int j0 = jj * 4;
    if (q.x == myidx) { cnt++; if (j0 + 0 < t) first = 0; }
    if (q.y == myidx) { cnt++; if (j0 + 1 < t) first = 0; }
    if (q.z == myidx) { cnt++; if (j0 + 2 < t) first = 0; }
    if (q.w == myidx) { cnt++; if (j0 + 3 < t) first = 0; }
  }
  if (t < SEQ && first) {
    const int owner = (myidx >> 2) & 255;
    const unsigned key = (unsigned)(((myidx >> 10) << 2) | (myidx & 3));
    const unsigned pos = atomicAdd(&nslot[owner], 1u);
    if (pos < H) {
      slots[pos * 256 + owner] = (key << 8) | (unsigned)cnt;
    } else {
      const unsigned o = atomicAdd(&ovfn, 1u);
      ovflist[o] = ((unsigned)myidx << 8) | (unsigned)cnt;
    }
  }
  __syncthreads();

  // Preload my 4 slot words into registers; read overflow count (final now).
  const unsigned s0 = slots[0 * 256 + t];
  const unsigned s1 = slots[1 * 256 + t];
  const unsigned s2 = slots[2 * 256 + t];
  const unsigned s3 = slots[3 * 256 + t];
  const unsigned novf = ovfn;

  // Phase C: pure register store stream. Per iteration: 1 cmp + 4 cndmask
  // per slot (c/sub hoisted as loop-invariant) + 1 global_store_dwordx4.
  // No LDS, no loads, nothing for the store to wait on.
  float4* __restrict__ o4 = (float4*)orow;
#define APPLY(s)                                        \
  do {                                                  \
    const bool m = ((s) >> 10) == (unsigned)k;          \
    const float c = (float)((s) & 255u);                \
    const unsigned sub = ((s) >> 8) & 3u;               \
    v.x = (m && sub == 0u) ? c : v.x;                   \
    v.y = (m && sub == 1u) ? c : v.y;                   \
    v.z = (m && sub == 2u) ? c : v.z;                   \
    v.w = (m && sub == 3u) ? c : v.w;                   \
  } while (0)
  for (int i = t; i < NF4; i += 256) {
    const int k = i >> 8;  // == per-thread sequence number (i = t + 256k)
    float4 v = make_float4(0.f, 0.f, 0.f, 0.f);
    APPLY(s0); APPLY(s1); APPLY(s2); APPLY(s3);
    o4[i] = v;
  }
#undef APPLY

  // Phase D: exact overflow patch (>4 distinct tokens on one owner thread;
  // ~1e-3 of threads). Block-uniform branch; barrier drains vmcnt so the
  // 4B patch stores land after the streamed lines.
  if (novf) {
    __syncthreads();
    for (unsigned j = t; j < novf; j += 256) {
      const unsigned e = ovflist[j];
      orow[e >> 8] = (float)(e & 255u);
    }
  }
}

extern "C" void kernel_launch(void* const* d_in, const int* in_sizes, int n_in,
                              void* d_out, int out_size, void* d_ws, size_t ws_size,
                              hipStream_t stream) {
  const int* x = (const int*)d_in[0];
  float* out = (float*)d_out;
  const int batch = in_sizes[0] / SEQ;  // 2048
  MultihotEmbedding_16458314678493_kernel<<<batch, 256, 0, stream>>>(x, out);
}